// Round 7
// baseline (192.792 us; speedup 1.0000x reference)
//
#include <hip/hip_runtime.h>

#define SEQ 200
#define HID 64
#define RPW 2                    // batch rows per wave
#define WPB 4                    // independent waves per block
#define NBLK (4096 / (RPW * WPB))   // 512 blocks -> 2 per CU, 8 waves/CU

typedef _Float16 f16;
typedef _Float16 f16x8 __attribute__((ext_vector_type(8)));
typedef float    f32x4 __attribute__((ext_vector_type(4)));

#define LOG2E 1.44269504088896340736f

#if __has_builtin(__builtin_amdgcn_exp2f)
#define EXP2F(x) __builtin_amdgcn_exp2f(x)
#else
#define EXP2F(x) __expf(0.69314718056f * (x))
#endif
#define RCPF(x) __builtin_amdgcn_rcpf(x)

// Pre-scaled domain: i/f/o gates scaled by log2e, g gate by 2*log2e
// (folded into W_hh/W_ih/bias at load time).
__device__ __forceinline__ float sigmoid_s(float s) {
    return RCPF(1.0f + EXP2F(-s));
}
__device__ __forceinline__ float tanh_s2(float s2) {
    return fmaf(-2.0f, RCPF(1.0f + EXP2F(s2)), 1.0f);
}

// Wave-local LSTM: each wave owns 2 batch rows and the FULL hidden state.
//  - whole W_hh^T (scaled) in registers: 16 N-tiles x 2 K-frags = 128 VGPR.
//  - 32 MFMAs/step (C rows 0,1 valid), gates redistributed through a
//    wave-private stride-40 LDS region (conflict-minimal), pointwise 2
//    cells/lane, h written back f16 into the swizzled A-frag buffer.
//  - NO __syncthreads in the 200-step loop: all loop state is wave-private;
//    same-wave DS ops execute in order. Single h buffer suffices.
__global__ __launch_bounds__(256, 2)
void qlstm_v7(const float* __restrict__ x,      // [4096, 200]
              const float* __restrict__ W_ih,   // [256]
              const float* __restrict__ W_hh,   // [256, 64]
              const float* __restrict__ b_ih,   // [256]
              const float* __restrict__ b_hh,   // [256]
              const float* __restrict__ W_lin,  // [200*64]
              const float* __restrict__ b_lin,  // [1]
              float* __restrict__ out)          // [4096]
{
    __shared__ float wl_lds[SEQ * HID];                     // 51.2 KB (block-shared, RO)
    __shared__ f16   h_frag[WPB][16 * HID];                 // 8 KB (wave-private)
    __shared__ __align__(16) char gates_lds[WPB][64 * 40];  // 10 KB (wave-private)
    __shared__ float x_lds[WPB][RPW * SEQ];                 // 6.4 KB (wave-private)

    const int tid = threadIdx.x;
    const int w   = tid >> 6;     // wave id (independent unit)
    const int l   = tid & 63;
    const int m   = l & 15;       // A row / B col within tile
    const int a   = l >> 4;       // k-group
    const int b0  = blockIdx.x * (RPW * WPB) + w * RPW;

    // quadrant pre-scales: i,f,o -> log2e ; g -> 2*log2e
    const float qs[4] = {LOG2E, LOG2E, 2.0f * LOG2E, LOG2E};

    // ---- stage W_lin cooperatively (only cross-wave shared data) ----
    {
        const float4* src = (const float4*)W_lin;
        float4* dst = (float4*)wl_lds;
        for (int i = tid; i < SEQ * HID / 4; i += 256) dst[i] = src[i];
    }
    // ---- stage this wave's 2 x-rows (400 contiguous floats) ----
    for (int i = l; i < RPW * SEQ; i += 64)
        x_lds[w][i] = x[(size_t)b0 * SEQ + i];
    // ---- zero this wave's h buffer (rows 2..15 stay zero forever) ----
    for (int i = l; i < (16 * HID) / 2; i += 64)
        ((float*)h_frag[w])[i] = 0.0f;

    // ---- all 16 B tiles (W_hh^T, pre-scaled) into registers ----
    // tile nt = q*4 + c: cols n = q*64 + c*16 + m, k = kk*32 + a*8 + e
    f16x8 Bf[16][2];
    #pragma unroll
    for (int nt = 0; nt < 16; ++nt) {
        const int q = nt >> 2, c = nt & 3;
        const int n = q * 64 + c * 16 + m;
        #pragma unroll
        for (int kk = 0; kk < 2; ++kk) {
            const float4* p = (const float4*)(W_hh + n * HID + kk * 32 + a * 8);
            float4 lo = p[0], hi = p[1];
            f16x8 f;
            f[0] = (f16)(lo.x * qs[q]); f[1] = (f16)(lo.y * qs[q]);
            f[2] = (f16)(lo.z * qs[q]); f[3] = (f16)(lo.w * qs[q]);
            f[4] = (f16)(hi.x * qs[q]); f[5] = (f16)(hi.y * qs[q]);
            f[6] = (f16)(hi.z * qs[q]); f[7] = (f16)(hi.w * qs[q]);
            Bf[nt][kk] = f;
        }
    }

    // ---- pointwise per-lane constants for j = l ----
    float wihp[4], biasp[4];
    #pragma unroll
    for (int q = 0; q < 4; ++q) {
        const int n = q * 64 + l;
        wihp[q]  = W_ih[n] * qs[q];
        biasp[q] = (b_ih[n] + b_hh[n]) * qs[q];
    }

    char* hb = (char*)h_frag[w];
    char* gb = (char*)gates_lds[w];
    // A-frag read addrs: row m, slot s = kk*4 + a, byte = m*128 + ((s^(m&7))<<4)
    const int ra0 = m * 128 + (((0 + a) ^ (m & 7)) << 4);
    const int ra1 = m * 128 + (((4 + a) ^ (m & 7)) << 4);
    // h write addrs for cells (b=0, j=l) and (b=1, j=l):
    // byte = b*128 + (((j>>3)^b)<<4) + (j&7)*2
    const int hw0 = ((l >> 3) << 4) + (l & 7) * 2;
    const int hw1 = 128 + ((((l >> 3)) ^ 1) << 4) + (l & 7) * 2;

    float c0 = 0.f, c1 = 0.f, o0 = 0.f, o1 = 0.f;
    const float t2s = 2.0f * LOG2E;

    __syncthreads();   // wl_lds ready; the ONLY block-wide barrier

    for (int t = 0; t < SEQ; ++t) {
        // ---- A fragments (this wave's h) ----
        const f16x8 A0 = *(const f16x8*)(hb + ra0);
        const f16x8 A1 = *(const f16x8*)(hb + ra1);
        const float wl = wl_lds[t * HID + l];
        const float x0 = x_lds[w][t];
        const float x1 = x_lds[w][SEQ + t];

        // ---- 32 MFMAs: all 256 gate columns for rows 0,1 ----
        f32x4 acc[16];
        #pragma unroll
        for (int nt = 0; nt < 16; ++nt) {
            f32x4 z = {0.f, 0.f, 0.f, 0.f};
            z       = __builtin_amdgcn_mfma_f32_16x16x32_f16(A0, Bf[nt][0], z, 0, 0, 0);
            acc[nt] = __builtin_amdgcn_mfma_f32_16x16x32_f16(A1, Bf[nt][1], z, 0, 0, 0);
        }

        // ---- in-wave gate scatter: lanes a==0 hold rows 0,1 in regs 0,1 ----
        // layout: float2 (row0,row1) at byte j*40 + q*8  (stride 40 -> exact-min banks)
        if (a == 0) {
            #pragma unroll
            for (int nt = 0; nt < 16; ++nt) {
                const int q = nt >> 2, c = nt & 3;
                const int j = c * 16 + m;
                *(float2*)(gb + j * 40 + q * 8) = make_float2(acc[nt][0], acc[nt][1]);
            }
        }
        __builtin_amdgcn_wave_barrier();   // order pin (same-wave DS is in-order)
        const float2 g0 = *(const float2*)(gb + l * 40 + 0);
        const float2 g1 = *(const float2*)(gb + l * 40 + 8);
        const float2 g2 = *(const float2*)(gb + l * 40 + 16);
        const float2 g3 = *(const float2*)(gb + l * 40 + 24);

        // ---- pointwise: 2 cells per lane (independent chains) ----
        {
            const float gi = sigmoid_s(g0.x + fmaf(x0, wihp[0], biasp[0]));
            const float gf = sigmoid_s(g1.x + fmaf(x0, wihp[1], biasp[1]));
            const float gg = tanh_s2  (g2.x + fmaf(x0, wihp[2], biasp[2]));
            const float go = sigmoid_s(g3.x + fmaf(x0, wihp[3], biasp[3]));
            c0 = fmaf(gf, c0, gi * gg);
            const float h = go * tanh_s2(t2s * c0);
            o0 = fmaf(h, wl, o0);
            *(f16*)(hb + hw0) = (f16)h;
        }
        {
            const float gi = sigmoid_s(g0.y + fmaf(x1, wihp[0], biasp[0]));
            const float gf = sigmoid_s(g1.y + fmaf(x1, wihp[1], biasp[1]));
            const float gg = tanh_s2  (g2.y + fmaf(x1, wihp[2], biasp[2]));
            const float go = sigmoid_s(g3.y + fmaf(x1, wihp[3], biasp[3]));
            c1 = fmaf(gf, c1, gi * gg);
            const float h = go * tanh_s2(t2s * c1);
            o1 = fmaf(h, wl, o1);
            *(f16*)(hb + hw1) = (f16)h;
        }
        // no barrier: next iteration's A-reads are same-wave ordered after h-writes
    }

    // ---- reduce o0,o1 over the 64 lanes (j) ----
    #pragma unroll
    for (int off = 1; off < 64; off <<= 1) {
        o0 += __shfl_xor(o0, off, 64);
        o1 += __shfl_xor(o1, off, 64);
    }
    if (l == 0) {
        const float bl = b_lin[0];
        out[b0]     = o0 + bl;
        out[b0 + 1] = o1 + bl;
    }
}

extern "C" void kernel_launch(void* const* d_in, const int* in_sizes, int n_in,
                              void* d_out, int out_size, void* d_ws, size_t ws_size,
                              hipStream_t stream) {
    const float* x     = (const float*)d_in[0];
    const float* W_ih  = (const float*)d_in[1];
    const float* W_hh  = (const float*)d_in[2];
    const float* b_ih  = (const float*)d_in[3];
    const float* b_hh  = (const float*)d_in[4];
    const float* W_lin = (const float*)d_in[5];
    const float* b_lin = (const float*)d_in[6];
    float* out = (float*)d_out;

    dim3 grid(NBLK);
    dim3 block(256);
    qlstm_v7<<<grid, block, 0, stream>>>(x, W_ih, W_hh, b_ih, b_hh,
                                         W_lin, b_lin, out);
}

// Round 11
// 115.974 us; speedup vs baseline: 1.6624x; 1.6624x over previous
//
#include <hip/hip_runtime.h>

#define SEQ 200
#define HID 64
#define BT  8
#define NBLK (4096 / BT)   // 512 blocks -> 2 per CU, 2 waves/SIMD

typedef _Float16 f16;
typedef _Float16 f16x8 __attribute__((ext_vector_type(8)));
typedef float    f32x4 __attribute__((ext_vector_type(4)));

#define LOG2E 1.44269504088896340736f

#if __has_builtin(__builtin_amdgcn_exp2f)
#define EXP2F(x) __builtin_amdgcn_exp2f(x)
#else
#define EXP2F(x) __expf(0.69314718056f * (x))
#endif
#define RCPF(x) __builtin_amdgcn_rcpf(x)

// Pre-scaled domain: i/f/o gates scaled by log2e, g gate by 2*log2e
// (folded into W_hh/W_ih/bias at load time).
__device__ __forceinline__ float sigmoid_s(float s) {
    return RCPF(1.0f + EXP2F(-s));
}
__device__ __forceinline__ float tanh_s2(float s2) {
    return fmaf(-2.0f, RCPF(1.0f + EXP2F(s2)), 1.0f);
}

// R6 structure, verbatim (proven passing at 128.9us):
//  - BT=8 rows/block, 512 blocks (2/CU, 2 waves/SIMD), one barrier/step.
//  - wave w owns j-cols [16w,16w+16) for all 4 quadrants: 8 MFMAs, C rows
//    0..7 valid (lane groups a=0,1 regs 0..3).
//  - half-swap via __shfl: lanes a>=2 pull C-regs 2,3 from lane l-32 ->
//    every lane runs exactly 2 cells.
//  - x*W_ih + bias folded into MFMA C-input.
//  - W_lin staged in LDS -> zero VMEM in the loop.
//  - h double-buffered in LDS (A-frag layout, XOR-swizzled 16B slots).
// SINGLE delta vs R6: s_setprio(1)/(0) around the ds_read->MFMA->merge
// region (bisect step; everything else byte-equivalent to R6).
__global__ __launch_bounds__(256, 2)
void qlstm_v11(const float* __restrict__ x,      // [4096, 200]
               const float* __restrict__ W_ih,   // [256]
               const float* __restrict__ W_hh,   // [256, 64]
               const float* __restrict__ b_ih,   // [256]
               const float* __restrict__ b_hh,   // [256]
               const float* __restrict__ W_lin,  // [200*64]
               const float* __restrict__ b_lin,  // [1]
               float* __restrict__ out)          // [4096]
{
    __shared__ float x_lds[16][201];        // 12.9 KB; rows 8..15 zero
    __shared__ f16   h_frag[2][16 * HID];   // 4 KB dbuf, swizzled frag layout
    __shared__ float wl_lds[SEQ * HID];     // 51.2 KB
    __shared__ float out_part[4][BT];

    const int tid = threadIdx.x;
    const int w   = tid >> 6;     // wave: j-block owner
    const int l   = tid & 63;
    const int m   = l & 15;       // B col / C col
    const int a   = l >> 4;       // k-group / C row-group
    const int b0  = blockIdx.x * BT;

    // quadrant pre-scales: i,f,o -> log2e ; g -> 2*log2e
    const float qs[4] = {LOG2E, LOG2E, 2.0f * LOG2E, LOG2E};

    // ---- stage x rows 0..7 (f32, coalesced) ----
    for (int i = tid; i < BT * SEQ; i += 256) {
        int b = i / SEQ, t = i - b * SEQ;
        x_lds[b][t] = x[(size_t)b0 * SEQ + i];
    }
    // ---- zero x rows 8..15 (flat; disjoint from staged rows) ----
    {
        float* z = &x_lds[8][0];
        for (int i = tid; i < 8 * 201; i += 256) z[i] = 0.0f;
    }
    // ---- stage W_lin (float4) ----
    {
        const float4* src = (const float4*)W_lin;
        float4* dst = (float4*)wl_lds;
        for (int i = tid; i < SEQ * HID / 4; i += 256) dst[i] = src[i];
    }
    // ---- zero both h buffers (rows 8..15 stay zero forever) ----
    for (int i = tid; i < 1024; i += 256) ((float*)h_frag)[i] = 0.0f;

    // ---- B fragments (W_hh^T, pre-scaled) once: col n=q*64+16w+m, k=kk*32+a*8+e ----
    f16x8 Bf[4][2];
    float wihq[4], biasq[4];
    #pragma unroll
    for (int q = 0; q < 4; ++q) {
        const int n = q * 64 + w * 16 + m;
        wihq[q]  = W_ih[n] * qs[q];
        biasq[q] = (b_ih[n] + b_hh[n]) * qs[q];
        #pragma unroll
        for (int kk = 0; kk < 2; ++kk) {
            const float4* p = (const float4*)(W_hh + n * HID + kk * 32 + a * 8);
            float4 lo = p[0], hi = p[1];
            f16x8 f;
            f[0] = (f16)(lo.x * qs[q]); f[1] = (f16)(lo.y * qs[q]);
            f[2] = (f16)(lo.z * qs[q]); f[3] = (f16)(lo.w * qs[q]);
            f[4] = (f16)(hi.x * qs[q]); f[5] = (f16)(hi.y * qs[q]);
            f[6] = (f16)(hi.z * qs[q]); f[7] = (f16)(hi.w * qs[q]);
            Bf[q][kk] = f;
        }
    }

    const int jpw = w * 16 + m;
    // A-frag read addrs: row m, slot s=kk*4+a, byte = m*128 + ((s^(m&7))<<4)
    const int ra0 = m * 128 + (((0 + a) ^ (m & 7)) << 4);
    const int ra1 = m * 128 + (((4 + a) ^ (m & 7)) << 4);
    // this lane's two cell rows after half-merge
    const int bA = 4 * (a & 1) + 2 * (a >> 1);   // a=0->0, a=1->4, a=2->2, a=3->6
    const int bB = bA + 1;
    // h write addrs: byte = b*128 + (((j>>3)^b)<<4) + (j&7)*2   (b<8 so b&7=b)
    const int hwaA = bA * 128 + (((jpw >> 3) ^ bA) << 4) + (jpw & 7) * 2;
    const int hwaB = bB * 128 + (((jpw >> 3) ^ bB) << 4) + (jpw & 7) * 2;

    const char* hbytes = (const char*)h_frag;

    float cA = 0.0f, cB = 0.0f, oA = 0.0f, oB = 0.0f;

    __syncthreads();

    for (int t = 0; t < SEQ; ++t) {
        const int rb = (t & 1) << 11;   // read-buffer byte offset

        // ======== gate GEMM (C-in = x*W_ih + bias) ========
        __builtin_amdgcn_s_setprio(1);
        const f16x8 A0 = *(const f16x8*)(hbytes + rb + ra0);
        const f16x8 A1 = *(const f16x8*)(hbytes + rb + ra1);
        float xr[4];
        #pragma unroll
        for (int r = 0; r < 4; ++r) xr[r] = x_lds[4 * a + r][t];   // rows>=8 read 0
        const float wl = wl_lds[t * HID + jpw];

        f32x4 acc[4];
        #pragma unroll
        for (int q = 0; q < 4; ++q) {
            f32x4 ini;
            #pragma unroll
            for (int r = 0; r < 4; ++r) ini[r] = fmaf(xr[r], wihq[q], biasq[q]);
            f32x4 z = __builtin_amdgcn_mfma_f32_16x16x32_f16(A0, Bf[q][0], ini, 0, 0, 0);
            acc[q]  = __builtin_amdgcn_mfma_f32_16x16x32_f16(A1, Bf[q][1], z, 0, 0, 0);
        }

        // ---- half-swap: lanes a>=2 take regs r=2,3 from lane l-32 ----
        float s2[4], s3[4];
        #pragma unroll
        for (int q = 0; q < 4; ++q) {
            s2[q] = __shfl(acc[q][2], l & 31, 64);
            s3[q] = __shfl(acc[q][3], l & 31, 64);
        }
        const bool lo = (a < 2);
        const float gA0 = lo ? acc[0][0] : s2[0];
        const float gA1 = lo ? acc[1][0] : s2[1];
        const float gA2 = lo ? acc[2][0] : s2[2];
        const float gA3 = lo ? acc[3][0] : s2[3];
        const float gB0 = lo ? acc[0][1] : s3[0];
        const float gB1 = lo ? acc[1][1] : s3[1];
        const float gB2 = lo ? acc[2][1] : s3[2];
        const float gB3 = lo ? acc[3][1] : s3[3];
        __builtin_amdgcn_s_setprio(0);

        // ======== pointwise: two cells per thread ========
        {
            const float gi = sigmoid_s(gA0);
            const float gf = sigmoid_s(gA1);
            const float gg = tanh_s2(gA2);
            const float go = sigmoid_s(gA3);
            cA = fmaf(gf, cA, gi * gg);
            const float h = go * tanh_s2((2.0f * LOG2E) * cA);
            oA = fmaf(h, wl, oA);
            *(f16*)((char*)h_frag + (rb ^ 2048) + hwaA) = (f16)h;
        }
        {
            const float gi = sigmoid_s(gB0);
            const float gf = sigmoid_s(gB1);
            const float gg = tanh_s2(gB2);
            const float go = sigmoid_s(gB3);
            cB = fmaf(gf, cB, gi * gg);
            const float h = go * tanh_s2((2.0f * LOG2E) * cB);
            oB = fmaf(h, wl, oB);
            *(f16*)((char*)h_frag + (rb ^ 2048) + hwaB) = (f16)h;
        }

        __syncthreads();   // h(write-buf) complete -> next step reads it
    }

    // ---- reduce over j: 16 lanes (m) in-wave, then 4 waves via LDS ----
    float vA = oA, vB = oB;
    #pragma unroll
    for (int off = 1; off < 16; off <<= 1) {
        vA += __shfl_xor(vA, off, 64);
        vB += __shfl_xor(vB, off, 64);
    }
    if (m == 0) {
        out_part[w][bA] = vA;
        out_part[w][bB] = vB;
    }
    __syncthreads();
    if (tid < BT) {
        out[b0 + tid] = out_part[0][tid] + out_part[1][tid]
                      + out_part[2][tid] + out_part[3][tid] + b_lin[0];
    }
}

extern "C" void kernel_launch(void* const* d_in, const int* in_sizes, int n_in,
                              void* d_out, int out_size, void* d_ws, size_t ws_size,
                              hipStream_t stream) {
    const float* x     = (const float*)d_in[0];
    const float* W_ih  = (const float*)d_in[1];
    const float* W_hh  = (const float*)d_in[2];
    const float* b_ih  = (const float*)d_in[3];
    const float* b_hh  = (const float*)d_in[4];
    const float* W_lin = (const float*)d_in[5];
    const float* b_lin = (const float*)d_in[6];
    float* out = (float*)d_out;

    dim3 grid(NBLK);
    dim3 block(256);
    qlstm_v11<<<grid, block, 0, stream>>>(x, W_ih, W_hh, b_ih, b_hh,
                                          W_lin, b_lin, out);
}

// Round 12
// 94.784 us; speedup vs baseline: 2.0340x; 1.2236x over previous
//
#include <hip/hip_runtime.h>

#define SEQ 200
#define HID 64
#define BT  8
#define NBLK (4096 / BT)   // 512 blocks -> 2 per CU, 2 waves/SIMD

typedef _Float16 f16;
typedef _Float16 f16x8 __attribute__((ext_vector_type(8)));
typedef float    f32x4 __attribute__((ext_vector_type(4)));

#define LOG2E 1.44269504088896340736f

#if __has_builtin(__builtin_amdgcn_exp2f)
#define EXP2F(x) __builtin_amdgcn_exp2f(x)
#else
#define EXP2F(x) __expf(0.69314718056f * (x))
#endif
#define RCPF(x) __builtin_amdgcn_rcpf(x)

// Pre-scaled domain: i/f/o gates scaled by log2e, g gate by 2*log2e
// (folded into W_hh/W_ih/bias at load time).
__device__ __forceinline__ float sigmoid_s(float s) {
    return RCPF(1.0f + EXP2F(-s));
}
__device__ __forceinline__ float tanh_s2(float s2) {
    return fmaf(-2.0f, RCPF(1.0f + EXP2F(s2)), 1.0f);
}

// R11 structure (proven, 116us) with ONE structural delta: sigma-duplicated
// A rows kill the shfl half-merge.
//   Fragment row r holds batch row sigma(r) = 2*(r>>2) + (r&1):
//   rows = [0,1,0,1, 2,3,2,3, 4,5,4,5, 6,7,6,7].
//   C-row 4a+r = gates of batch 2a+(r&1)  ->  lane group a reads its two
//   cells (2a, j), (2a+1, j) DIRECTLY from acc regs 0,1. No shfl, no selects,
//   all 64 lanes active in pointwise. Each h is written to 2 fragment slots
//   (rows 4a+{0,2} for batch 2a, rows 4a+{1,3} for batch 2a+1).
// Other deltas: none (setprio, W_lin LDS, h dbuf + XOR swizzle as R11).
// c_state kept pre-scaled by 2*log2e (drops one mul from the c->tanh chain).
__global__ __launch_bounds__(256, 2)
void qlstm_v12(const float* __restrict__ x,      // [4096, 200]
               const float* __restrict__ W_ih,   // [256]
               const float* __restrict__ W_hh,   // [256, 64]
               const float* __restrict__ b_ih,   // [256]
               const float* __restrict__ b_hh,   // [256]
               const float* __restrict__ W_lin,  // [200*64]
               const float* __restrict__ b_lin,  // [1]
               float* __restrict__ out)          // [4096]
{
    __shared__ float x_lds[BT][201];        // 6.3 KB (only rows 0..7 needed now)
    __shared__ f16   h_frag[2][16 * HID];   // 4 KB dbuf, swizzled frag layout
    __shared__ float wl_lds[SEQ * HID];     // 51.2 KB
    __shared__ float out_part[4][BT];

    const int tid = threadIdx.x;
    const int w   = tid >> 6;     // wave: j-block owner
    const int l   = tid & 63;
    const int m   = l & 15;       // B col / C col
    const int a   = l >> 4;       // k-group / C row-group
    const int b0  = blockIdx.x * BT;

    // quadrant pre-scales: i,f,o -> log2e ; g -> 2*log2e
    const float qs[4] = {LOG2E, LOG2E, 2.0f * LOG2E, LOG2E};

    // ---- stage x rows 0..7 (f32, coalesced) ----
    for (int i = tid; i < BT * SEQ; i += 256) {
        int b = i / SEQ, t = i - b * SEQ;
        x_lds[b][t] = x[(size_t)b0 * SEQ + i];
    }
    // ---- stage W_lin (float4) ----
    {
        const float4* src = (const float4*)W_lin;
        float4* dst = (float4*)wl_lds;
        for (int i = tid; i < SEQ * HID / 4; i += 256) dst[i] = src[i];
    }
    // ---- zero both h buffers (h0 = 0; sigma-consistent) ----
    for (int i = tid; i < 1024; i += 256) ((float*)h_frag)[i] = 0.0f;

    // ---- B fragments (W_hh^T, pre-scaled) once: col n=q*64+16w+m, k=kk*32+a*8+e ----
    f16x8 Bf[4][2];
    float wihq[4], biasq[4];
    #pragma unroll
    for (int q = 0; q < 4; ++q) {
        const int n = q * 64 + w * 16 + m;
        wihq[q]  = W_ih[n] * qs[q];
        biasq[q] = (b_ih[n] + b_hh[n]) * qs[q];
        #pragma unroll
        for (int kk = 0; kk < 2; ++kk) {
            const float4* p = (const float4*)(W_hh + n * HID + kk * 32 + a * 8);
            float4 lo = p[0], hi = p[1];
            f16x8 f;
            f[0] = (f16)(lo.x * qs[q]); f[1] = (f16)(lo.y * qs[q]);
            f[2] = (f16)(lo.z * qs[q]); f[3] = (f16)(lo.w * qs[q]);
            f[4] = (f16)(hi.x * qs[q]); f[5] = (f16)(hi.y * qs[q]);
            f[6] = (f16)(hi.z * qs[q]); f[7] = (f16)(hi.w * qs[q]);
            Bf[q][kk] = f;
        }
    }

    const int jpw = w * 16 + m;
    // A-frag read addrs: row m, slot s=kk*4+a, byte = m*128 + ((s^(m&7))<<4)
    const int ra0 = m * 128 + (((0 + a) ^ (m & 7)) << 4);
    const int ra1 = m * 128 + (((4 + a) ^ (m & 7)) << 4);
    // this lane's two batch rows (direct from C regs 0,1 — no merge)
    const int bA = 2 * a;        // from acc reg 0 (and dup reg 2)
    const int bB = 2 * a + 1;    // from acc reg 1 (and dup reg 3)
    // h write addrs: batch bA lives at fragment rows 4a, 4a+2; bB at 4a+1, 4a+3.
    // byte(R, j) = R*128 + (((j>>3) ^ (R&7))<<4) + (j&7)*2
    int hwr[4];
    #pragma unroll
    for (int r = 0; r < 4; ++r) {
        const int R = 4 * a + r;
        hwr[r] = R * 128 + ((((jpw >> 3) ^ (R & 7))) << 4) + (jpw & 7) * 2;
    }

    const char* hbytes = (const char*)h_frag;

    float cA = 0.0f, cB = 0.0f, oA = 0.0f, oB = 0.0f;
    const float t2s = 2.0f * LOG2E;

    __syncthreads();

    for (int t = 0; t < SEQ; ++t) {
        const int rb = (t & 1) << 11;   // read-buffer byte offset
        const int wb = rb ^ 2048;       // write-buffer byte offset

        // ======== gate GEMM (C-in = x*W_ih + bias, sigma-row mapping) ========
        __builtin_amdgcn_s_setprio(1);
        const f16x8 A0 = *(const f16x8*)(hbytes + rb + ra0);
        const f16x8 A1 = *(const f16x8*)(hbytes + rb + ra1);
        const float x0 = x_lds[bA][t];
        const float x1 = x_lds[bB][t];
        const float wl = wl_lds[t * HID + jpw];

        f32x4 acc[4];
        #pragma unroll
        for (int q = 0; q < 4; ++q) {
            const float i0 = fmaf(x0, wihq[q], biasq[q]);
            const float i1 = fmaf(x1, wihq[q], biasq[q]);
            f32x4 ini;
            ini[0] = i0; ini[1] = i1; ini[2] = i0; ini[3] = i1;
            f32x4 z = __builtin_amdgcn_mfma_f32_16x16x32_f16(A0, Bf[q][0], ini, 0, 0, 0);
            acc[q]  = __builtin_amdgcn_mfma_f32_16x16x32_f16(A1, Bf[q][1], z, 0, 0, 0);
        }
        __builtin_amdgcn_s_setprio(0);

        // ======== pointwise: two cells per thread, gates direct from regs ========
        {
            const float gi = sigmoid_s(acc[0][0]);
            const float gf = sigmoid_s(acc[1][0]);
            const float gg = tanh_s2(acc[2][0]);
            const float go = sigmoid_s(acc[3][0]);
            cA = fmaf(gf, cA, t2s * (gi * gg));    // cA pre-scaled by 2*log2e
            const float h = go * tanh_s2(cA);
            const f16 hf = (f16)h;
            *(f16*)((char*)h_frag + wb + hwr[0]) = hf;
            *(f16*)((char*)h_frag + wb + hwr[2]) = hf;
            oA = fmaf(h, wl, oA);
        }
        {
            const float gi = sigmoid_s(acc[0][1]);
            const float gf = sigmoid_s(acc[1][1]);
            const float gg = tanh_s2(acc[2][1]);
            const float go = sigmoid_s(acc[3][1]);
            cB = fmaf(gf, cB, t2s * (gi * gg));
            const float h = go * tanh_s2(cB);
            const f16 hf = (f16)h;
            *(f16*)((char*)h_frag + wb + hwr[1]) = hf;
            *(f16*)((char*)h_frag + wb + hwr[3]) = hf;
            oB = fmaf(h, wl, oB);
        }

        __syncthreads();   // h(write-buf) complete -> next step reads it
    }

    // ---- reduce over j: 16 lanes (m) in-wave, then 4 waves via LDS ----
    float vA = oA, vB = oB;
    #pragma unroll
    for (int off = 1; off < 16; off <<= 1) {
        vA += __shfl_xor(vA, off, 64);
        vB += __shfl_xor(vB, off, 64);
    }
    if (m == 0) {
        out_part[w][bA] = vA;
        out_part[w][bB] = vB;
    }
    __syncthreads();
    if (tid < BT) {
        out[b0 + tid] = out_part[0][tid] + out_part[1][tid]
                      + out_part[2][tid] + out_part[3][tid] + b_lin[0];
    }
}

extern "C" void kernel_launch(void* const* d_in, const int* in_sizes, int n_in,
                              void* d_out, int out_size, void* d_ws, size_t ws_size,
                              hipStream_t stream) {
    const float* x     = (const float*)d_in[0];
    const float* W_ih  = (const float*)d_in[1];
    const float* W_hh  = (const float*)d_in[2];
    const float* b_ih  = (const float*)d_in[3];
    const float* b_hh  = (const float*)d_in[4];
    const float* W_lin = (const float*)d_in[5];
    const float* b_lin = (const float*)d_in[6];
    float* out = (float*)d_out;

    dim3 grid(NBLK);
    dim3 block(256);
    qlstm_v12<<<grid, block, 0, stream>>>(x, W_ih, W_hh, b_ih, b_hh,
                                          W_lin, b_lin, out);
}